// Round 7
// baseline (19.832 us; speedup 1.0000x reference)
//
#include <hip/hip_runtime.h>
#include <math.h>

#define LL 50
#define DD 50
#define RR 3
#define CC 10

// ---------------- Kernel 1: dtab[v] = (row_v.w0, row_v.w1, row_v.w2, 0) ----
// 4 lanes per vocab row (~24 waves/CU). Lane q handles float2-pairs
// [s, s+c): q0:0..6, q1:7..12, q2:13..18, q3:19..24. W staged in LDS.
__global__ __launch_bounds__(256) void precompute_dots_kernel(
    const float* __restrict__ emb_table,  // [VOCAB, D]
    const float* __restrict__ W,          // [150]
    float4*      __restrict__ dtab,       // [VOCAB]
    int vocab)
{
    __shared__ float sW[RR * DD];
    if (threadIdx.x < RR * DD) sW[threadIdx.x] = W[threadIdx.x];
    __syncthreads();

    const int tid = blockIdx.x * 256 + threadIdx.x;
    const int r   = tid >> 2;          // row
    const int q   = tid & 3;           // quarter
    if (r >= vocab) return;            // whole 4-lane group exits together

    const float2* p = reinterpret_cast<const float2*>(emb_table + (size_t)r * DD);
    const int s = 6 * q + (q > 0 ? 1 : 0);   // 0,7,13,19
    const int c = (q == 0) ? 7 : 6;

    float d0 = 0.f, d1 = 0.f, d2 = 0.f;
    #pragma unroll
    for (int k = 0; k < 7; ++k) {
        if (k < c) {
            float2 e = p[s + k];
            int j = 2 * (s + k);
            d0 = fmaf(e.x, sW[          j], fmaf(e.y, sW[          j + 1], d0));
            d1 = fmaf(e.x, sW[    DD  + j], fmaf(e.y, sW[    DD  + j + 1], d1));
            d2 = fmaf(e.x, sW[2 * DD  + j], fmaf(e.y, sW[2 * DD  + j + 1], d2));
        }
    }
    d0 += __shfl_xor(d0, 1); d0 += __shfl_xor(d0, 2);
    d1 += __shfl_xor(d1, 1); d1 += __shfl_xor(d1, 2);
    d2 += __shfl_xor(d2, 1); d2 += __shfl_xor(d2, 2);
    if (q == 0) dtab[r] = make_float4(d0, d1, d2, 0.f);
}

// ---------------- Kernel 2: thread-per-combo-ELEMENT, 2 samples/wave -------
// Half-wave (32 lanes) = 1 sample; lane e<30 owns (combo e/3, element e%3).
// combo_idx load is fully coalesced; then one x gather, one mask gather, one
// 4B dtab gather per thread. Triple-sum via 2 shfl_down, sigmoid on e%3==0,
// 5-step shfl_xor butterfly per half sums the 10 combos.
__global__ __launch_bounds__(256) void combo_eval_kernel(
    const int*   __restrict__ x,          // [B, L]
    const float* __restrict__ emb_mask,   // [B, L]
    const int*   __restrict__ combo_idx,  // [B, C, R]
    const float* __restrict__ dtabf,      // [VOCAB*4]: component rr at 4*row+rr
    const float* __restrict__ bvec,       // [1]
    float*       __restrict__ out,        // [B]
    int B)
{
    const int lane = threadIdx.x & 63;
    const int wid  = (blockIdx.x << 2) + (threadIdx.x >> 6);  // global wave id
    const int half = lane >> 5;
    const int e    = lane & 31;           // element slot, 0..29 active
    const int b    = wid * 2 + half;
    const float bias = bvec[0];

    float v = 0.f;
    const bool act = (b < B) && (e < CC * RR);
    if (act) {
        int i   = combo_idx[b * (CC * RR) + e];   // coalesced (30 consecutive)
        int rr  = e - (e / 3) * 3;                // e % 3
        int row = x[b * LL + i];                  // gather within 200B row
        float m = emb_mask[b * LL + i];           // gather within 200B row
        v = dtabf[4 * row + rr] * m;              // 4B gather, L2-resident
    }

    // Triple-sum of original v onto lanes e%3==0 (lanes 30,31 carry v=0).
    float v1 = __shfl_down(v, 1);
    float v2 = __shfl_down(v, 2);
    float sacc = v + v1 + v2 + bias;

    float sig = 0.f;
    if (act && (e - (e / 3) * 3) == 0)
        sig = __builtin_amdgcn_rcpf(1.0f + __expf(-sacc));

    // Butterfly within each 32-lane half (xor masks <32 never cross halves).
    sig += __shfl_xor(sig, 16);
    sig += __shfl_xor(sig,  8);
    sig += __shfl_xor(sig,  4);
    sig += __shfl_xor(sig,  2);
    sig += __shfl_xor(sig,  1);
    if (e == 0 && b < B) out[b] = sig;
}

extern "C" void kernel_launch(void* const* d_in, const int* in_sizes, int n_in,
                              void* d_out, int out_size, void* d_ws, size_t ws_size,
                              hipStream_t stream) {
    const int*   x         = (const int*)d_in[0];
    const float* emb_mask  = (const float*)d_in[1];
    const int*   combo_idx = (const int*)d_in[2];
    // d_in[3] = step (unused)
    const float* emb_table = (const float*)d_in[4];
    const float* W         = (const float*)d_in[5];
    const float* bvec      = (const float*)d_in[6];
    float*       out       = (float*)d_out;

    const int B     = out_size;            // OUT == 1
    const int vocab = in_sizes[4] / DD;    // emb_table is [VOCAB, D]

    float4* dtab = (float4*)d_ws;          // 16 * VOCAB = 1.6 MB scratch

    const int pc_threads = 4 * vocab;
    precompute_dots_kernel<<<(pc_threads + 255) / 256, 256, 0, stream>>>(
        emb_table, W, dtab, vocab);

    // 2 samples per wave, 4 waves per block -> 8 samples per block.
    const int spb = 8;
    combo_eval_kernel<<<(B + spb - 1) / spb, 256, 0, stream>>>(
        x, emb_mask, combo_idx, (const float*)dtab, bvec, out, B);
}

// Round 8
// 19.118 us; speedup vs baseline: 1.0374x; 1.0374x over previous
//
#include <hip/hip_runtime.h>
#include <math.h>

#define LL 50
#define DD 50
#define RR 3
#define CC 10
#define SPB 16   // samples per block in kernel 2 (4 waves * 4 samples)

// ---------------- Kernel 1: dtab[v] = (row_v.w0, row_v.w1, row_v.w2, 0) ----
// 4 lanes per vocab row (~24 waves/CU). Lane q handles float2-pairs
// [s, s+c): q0:0..6, q1:7..12, q2:13..18, q3:19..24. W staged in LDS.
__global__ __launch_bounds__(256) void precompute_dots_kernel(
    const float* __restrict__ emb_table,  // [VOCAB, D]
    const float* __restrict__ W,          // [150]
    float4*      __restrict__ dtab,       // [VOCAB]
    int vocab)
{
    __shared__ float sW[RR * DD];
    if (threadIdx.x < RR * DD) sW[threadIdx.x] = W[threadIdx.x];
    __syncthreads();

    const int tid = blockIdx.x * 256 + threadIdx.x;
    const int r   = tid >> 2;          // row
    const int q   = tid & 3;           // quarter
    if (r >= vocab) return;            // whole 4-lane group exits together

    const float2* p = reinterpret_cast<const float2*>(emb_table + (size_t)r * DD);
    const int s = 6 * q + (q > 0 ? 1 : 0);   // 0,7,13,19
    const int c = (q == 0) ? 7 : 6;

    float d0 = 0.f, d1 = 0.f, d2 = 0.f;
    #pragma unroll
    for (int k = 0; k < 7; ++k) {
        if (k < c) {
            float2 e = p[s + k];
            int j = 2 * (s + k);
            d0 = fmaf(e.x, sW[          j], fmaf(e.y, sW[          j + 1], d0));
            d1 = fmaf(e.x, sW[    DD  + j], fmaf(e.y, sW[    DD  + j + 1], d1));
            d2 = fmaf(e.x, sW[2 * DD  + j], fmaf(e.y, sW[2 * DD  + j + 1], d2));
        }
    }
    d0 += __shfl_xor(d0, 1); d0 += __shfl_xor(d0, 2);
    d1 += __shfl_xor(d1, 1); d1 += __shfl_xor(d1, 2);
    d2 += __shfl_xor(d2, 1); d2 += __shfl_xor(d2, 2);
    if (q == 0) dtab[r] = make_float4(d0, d1, d2, 0.f);
}

// ---------------- Kernel 2: thread-per-combo + LDS-staged x/mask ----------
// Block = 16 samples. Stage x/mask (16*50 ints + floats) via one int4/float4
// load per thread (fully coalesced), then lane c<10 of each 16-lane group
// evaluates one combo: coalesced-ish combo load, 6 LDS lookups, 3 dtab
// component gathers (L2-resident 1.6MB), sigmoid, 16-lane shfl tree.
__global__ __launch_bounds__(256) void combo_eval_kernel(
    const int*   __restrict__ x,          // [B, L]
    const float* __restrict__ emb_mask,   // [B, L]
    const int*   __restrict__ combo_idx,  // [B, C, R]
    const float* __restrict__ dtabf,      // [VOCAB*4]: component rr at 4*row+rr
    const float* __restrict__ bvec,       // [1]
    float*       __restrict__ out,        // [B]
    int B)
{
    __shared__ int   s_x[SPB * LL];       // 800 ints
    __shared__ float s_m[SPB * LL];       // 800 floats

    const int tid = threadIdx.x;
    const int b0  = blockIdx.x * SPB;

    // Coalesced stage: 16 samples * 50 = 800 elems = 200 vec4 per array.
    // b0*LL*4 bytes = 3200*blockIdx -> 16B-aligned. One vec4 load per thread.
    if (tid < SPB * LL / 4) {
        reinterpret_cast<int4*>(s_x)[tid] =
            reinterpret_cast<const int4*>(x + (size_t)b0 * LL)[tid];
        reinterpret_cast<float4*>(s_m)[tid] =
            reinterpret_cast<const float4*>(emb_mask + (size_t)b0 * LL)[tid];
    }
    __syncthreads();

    const int lane = tid & 63;
    const int sid  = ((tid >> 6) << 2) + (lane >> 4);   // sample in block, 0..15
    const int c    = lane & 15;                          // combo, <10 active
    const int b    = b0 + sid;

    float v = 0.f;
    if (b < B && c < CC) {
        const int* cp = combo_idx + ((size_t)b * CC + c) * RR;
        int i0 = cp[0];
        int i1 = cp[1];
        int i2 = cp[2];
        const int base = sid * LL;
        int   r0 = s_x[base + i0], r1 = s_x[base + i1], r2 = s_x[base + i2];
        float m0 = s_m[base + i0], m1 = s_m[base + i1], m2 = s_m[base + i2];
        float sacc = dtabf[4 * r0 + 0] * m0
                   + dtabf[4 * r1 + 1] * m1
                   + dtabf[4 * r2 + 2] * m2
                   + bvec[0];
        v = __builtin_amdgcn_rcpf(1.0f + __expf(-sacc));
    }
    // Sum within each 16-lane group (lanes c>=10 carry zeros).
    v += __shfl_down(v, 8);
    v += __shfl_down(v, 4);
    v += __shfl_down(v, 2);
    v += __shfl_down(v, 1);
    if (c == 0 && b < B) out[b] = v;
}

extern "C" void kernel_launch(void* const* d_in, const int* in_sizes, int n_in,
                              void* d_out, int out_size, void* d_ws, size_t ws_size,
                              hipStream_t stream) {
    const int*   x         = (const int*)d_in[0];
    const float* emb_mask  = (const float*)d_in[1];
    const int*   combo_idx = (const int*)d_in[2];
    // d_in[3] = step (unused)
    const float* emb_table = (const float*)d_in[4];
    const float* W         = (const float*)d_in[5];
    const float* bvec      = (const float*)d_in[6];
    float*       out       = (float*)d_out;

    const int B     = out_size;            // OUT == 1
    const int vocab = in_sizes[4] / DD;    // emb_table is [VOCAB, D]

    float4* dtab = (float4*)d_ws;          // 16 * VOCAB = 1.6 MB scratch

    const int pc_threads = 4 * vocab;
    precompute_dots_kernel<<<(pc_threads + 255) / 256, 256, 0, stream>>>(
        emb_table, W, dtab, vocab);

    combo_eval_kernel<<<(B + SPB - 1) / SPB, 256, 0, stream>>>(
        x, emb_mask, combo_idx, (const float*)dtab, bvec, out, B);
}